// Round 5
// baseline (637.826 us; speedup 1.0000x reference)
//
#include <hip/hip_runtime.h>
#include <hip/hip_bf16.h>

typedef __hip_bfloat16 bf16;
typedef __attribute__((ext_vector_type(8))) short bf16x8;   // 8 bf16 = 4 VGPRs (MFMA A/B frag)
typedef __attribute__((ext_vector_type(4))) float f32x4;    // MFMA C/D frag

#define ASYNC_CP16(gsrc, ldst)                                                              \
  __builtin_amdgcn_global_load_lds(                                                         \
      (const __attribute__((address_space(1))) unsigned int*)(gsrc),                        \
      (__attribute__((address_space(3))) unsigned int*)(ldst), 16, 0, 0)

#define BB 32
#define NN 1024
#define FF 512
#define HH 2048
#define M_ROWS (BB * NN)  // 32768

// ---------------------------------------------------------------- weight casts (fused)
__global__ __launch_bounds__(256) void cvt_pair(const float* __restrict__ a, bf16* __restrict__ da,
                                                const float* __restrict__ b, bf16* __restrict__ db,
                                                int n) {
  int i = blockIdx.x * 256 + threadIdx.x;
  if (i < n) {
    da[i] = __float2bfloat16(a[i]);
    db[i] = __float2bfloat16(b[i]);
  }
}

// ---------------------------------------------------------------- cross-lane xor via LDS crossbar
template <int IMM>
__device__ __forceinline__ unsigned long long swz64(unsigned long long k) {
  int lo = __builtin_amdgcn_ds_swizzle((int)(unsigned)k, IMM);
  int hi = __builtin_amdgcn_ds_swizzle((int)(unsigned)(k >> 32), IMM);
  return (((unsigned long long)(unsigned)hi) << 32) | (unsigned)lo;
}

// ---------------------------------------------------------------- stable argsort per row
// (unchanged from R3 passing version)
__global__ __launch_bounds__(256) void sort_rows_wave(const float* __restrict__ x,
                                                      unsigned* __restrict__ xs_pack,
                                                      unsigned* __restrict__ srt_pack) {
  __shared__ __align__(16) unsigned short scatx[4 * FF];
  const int t = threadIdx.x;
  const int lane = t & 63;
  const int w = t >> 6;
  const size_t row = (size_t)blockIdx.x * 4 + w;
  const float* xr = x + row * FF;

  float4 v0 = *(const float4*)(xr + lane * 8);
  float4 v1 = *(const float4*)(xr + lane * 8 + 4);
  float vals[8] = {v0.x, v0.y, v0.z, v0.w, v1.x, v1.y, v1.z, v1.w};

  unsigned long long key[8];
#pragma unroll
  for (int r = 0; r < 8; r++) {
    unsigned u = __float_as_uint(vals[r]);
    unsigned s = u ^ ((unsigned)((int)u >> 31) | 0x80000000u);  // monotone fp32->u32
    key[r] = ((unsigned long long)s << 32) | (unsigned)(lane * 8 + r);
  }

#pragma unroll
  for (int k = 2; k <= 512; k <<= 1) {
#pragma unroll
    for (int j = k >> 1; j > 0; j >>= 1) {
      if (j >= 8) {
        const int d = j >> 3;
        unsigned long long o[8];
#pragma unroll
        for (int r = 0; r < 8; r++) {
          if (d == 1)       o[r] = swz64<0x041F>(key[r]);
          else if (d == 2)  o[r] = swz64<0x081F>(key[r]);
          else if (d == 4)  o[r] = swz64<0x101F>(key[r]);
          else if (d == 8)  o[r] = swz64<0x201F>(key[r]);
          else if (d == 16) o[r] = swz64<0x401F>(key[r]);
          else              o[r] = __shfl_xor(key[r], 32, 64);
        }
        bool asc = (((lane * 8) & k) == 0);
        bool lower = ((lane & d) == 0);
        bool keep = (asc == lower);
#pragma unroll
        for (int r = 0; r < 8; r++) {
          bool mine = key[r] < o[r];
          key[r] = (mine == keep) ? key[r] : o[r];
        }
      } else {
#pragma unroll
        for (int r = 0; r < 8; r++) {
          if ((r & j) == 0) {
            const int a = r, b = r | j;
            bool asc = (((lane * 8 + a) & k) == 0);
            unsigned long long ka = key[a], kb = key[b];
            bool sw = ((ka > kb) == asc);
            key[a] = sw ? kb : ka;
            key[b] = sw ? ka : kb;
          }
        }
      }
    }
  }

  const int base = w * FF;
  unsigned j8[8];
#pragma unroll
  for (int r = 0; r < 8; r++) {
    j8[r] = (unsigned)key[r] & 0xFFFFu;
    __hip_bfloat16 hb = __float2bfloat16(vals[r]);
    scatx[base + j8[r]] = *(unsigned short*)&hb;
  }

  uint4 so;
  so.x = j8[0] | (j8[1] << 16);
  so.y = j8[2] | (j8[3] << 16);
  so.z = j8[4] | (j8[5] << 16);
  so.w = j8[6] | (j8[7] << 16);
  *(uint4*)(srt_pack + row * 256 + lane * 4) = so;

  __syncthreads();
  uint4 xo = *(const uint4*)&scatx[base + lane * 8];
  *(uint4*)(xs_pack + row * 256 + lane * 4) = xo;
}

// ---------------------------------------------------------------- fused MLP kernel
// One block = one 128-row M-panel; grid = 256 = 1 block/CU, 1 round.
// Loop ht = 0..15 over 128-wide H-tiles:
//   h-part : ha[128x128] = xs[128x512] @ W1[ht-rows]^T   (8 k-chunks of 64, XS/W1 LDS dbuf)
//            SWAPPED mfma(A=W1frag, B=xsfrag) -> D[row=H][col=M]: lane holds 4 H-consec
//            per M -> +b1, relu, pack, ONE ds_write_b64/quad into swizzled h[128][128].
//   z-part : za[128x512] += h_tile @ W2[:,ht-slice]^T    (4 k-chunks of 32, W2 LDS dbuf)
//            normal mfma(A=hfrag, B=W2frag) -> D[row=M][col=F] (verified epilogue layout).
// h never touches global memory. za persistent in VGPRs (128/thread).
// LDS (exact 160 KiB): XS dbuf 2x16K | W1 dbuf 2x16K | W2 dbuf 2x32K | h 32K.
// Swizzles: [r][64] bufs: slot' = slot ^ (row&7); [r][32] bufs: slot' = slot ^ ((row>>1)&3)
// (the verified gemm8p scheme); h[128][128]: 16B-slot' = slot ^ (M&7). All staging via
// pre-swizzled global source + linear CP16 dest (rule #21).
// Schedule: proven 2-barrier chunk {reads; stage next; barrier; lgkm0; setprio1; MFMA;
// setprio0; vmcnt(counted); barrier}; W2-zc0 staged early at kc==6 (vmcnt(4) there).
__global__ __launch_bounds__(512, 2) void fused_mlp(const bf16* __restrict__ xsb,
                                                    const bf16* __restrict__ W1b,
                                                    const float* __restrict__ b1,
                                                    const bf16* __restrict__ W2b,
                                                    const float* __restrict__ b2,
                                                    bf16* __restrict__ Z) {
  __shared__ __align__(16) unsigned char S[163840];
  // region offsets (bytes)
  const int XSO = 0;        // 2 x 16384
  const int W1O = 32768;    // 2 x 16384
  const int W2O = 65536;    // 2 x 32768
  const int HOF = 131072;   // 32768

  const int t = threadIdx.x;
  const int lane = t & 63, wave = t >> 6;
  const int waveM = wave >> 2, waveN = wave & 3;
  const int fr = lane & 15, q = lane >> 4;
  const int m0 = (int)blockIdx.x * 128;

  // --- staging thread mapping, [128 rows][64 elem] bufs (XS, W1): unit u = j*512+t, j=0..1
  //     row = u>>3 (j=0: 0..63, j=1: 64..127), slot3 = (t&7)^(row&7)  (j-invariant, 64%8==0)
  const int r64 = t >> 3;                       // 0..63
  const int sl3 = (t & 7) ^ (r64 & 7);
  const bf16* xsg0 = xsb + (size_t)(m0 + r64) * FF + sl3 * 8;          // + kc*64; j=1: +64*FF
  const bf16* w1g0 = W1b + (size_t)r64 * FF + sl3 * 8;                 // + (ht*128)*FF + kc*64
  // --- [512 rows][32 elem] buf (W2): unit u = j*512+t, j=0..3; row = 128j + (t>>2)
  const int r32 = t >> 2;                       // 0..127
  const int sl2 = (t & 3) ^ ((t >> 3) & 3);
  const bf16* w2g0 = W2b + (size_t)r32 * HH + sl2 * 8;                 // + j*128*HH + ht*128 + zc*32

#define STAGE_XS(kc_)                                                        \
  do {                                                                       \
    const int d_ = XSO + ((kc_) & 1) * 16384 + t * 16;                       \
    const bf16* g_ = xsg0 + (kc_) * 64;                                      \
    ASYNC_CP16(g_, &S[d_]);                                                  \
    ASYNC_CP16(g_ + (size_t)64 * FF, &S[d_ + 8192]);                         \
  } while (0)
#define STAGE_W1(ht_, kc_)                                                   \
  do {                                                                       \
    const int d_ = W1O + ((kc_) & 1) * 16384 + t * 16;                       \
    const bf16* g_ = w1g0 + (size_t)(ht_) * 128 * FF + (kc_) * 64;           \
    ASYNC_CP16(g_, &S[d_]);                                                  \
    ASYNC_CP16(g_ + (size_t)64 * FF, &S[d_ + 8192]);                         \
  } while (0)
#define STAGE_W2(ht_, zc_)                                                   \
  do {                                                                       \
    const int d_ = W2O + ((zc_) & 1) * 32768 + t * 16;                       \
    const bf16* g_ = w2g0 + (ht_) * 128 + (zc_) * 32;                        \
    ASYNC_CP16(g_, &S[d_]);                                                  \
    ASYNC_CP16(g_ + (size_t)128 * HH, &S[d_ + 8192]);                        \
    ASYNC_CP16(g_ + (size_t)256 * HH, &S[d_ + 16384]);                       \
    ASYNC_CP16(g_ + (size_t)384 * HH, &S[d_ + 24576]);                       \
  } while (0)

  f32x4 zero = {0.f, 0.f, 0.f, 0.f};
  f32x4 za[4][8];   // persistent z accumulator: rows M (4 Mt), cols F (8 Ft)
  f32x4 ha[4][2];   // per-ht h accumulator: D[row=H][col=M] -> [Mt][Ht]
#pragma unroll
  for (int i = 0; i < 4; i++)
#pragma unroll
    for (int j = 0; j < 8; j++) za[i][j] = zero;
#pragma unroll
  for (int i = 0; i < 4; i++)
#pragma unroll
    for (int j = 0; j < 2; j++) ha[i][j] = zero;

  // prologue: stage first XS/W1 chunk
  STAGE_XS(0);
  STAGE_W1(0, 0);
  asm volatile("s_waitcnt vmcnt(0)" ::: "memory");
  __builtin_amdgcn_s_barrier();

  for (int ht = 0; ht < 16; ++ht) {
    // ================= h-part: 8 chunks of BK=64 =================
    for (int kc = 0; kc < 8; ++kc) {
      const int xo = XSO + (kc & 1) * 16384;
      const int wo = W1O + (kc & 1) * 16384;
      bf16x8 aw[2][2], bx[2][4];
#pragma unroll
      for (int ks = 0; ks < 2; ks++) {
#pragma unroll
        for (int Ht = 0; Ht < 2; Ht++) {
          const int row = waveN * 32 + Ht * 16 + fr;
          aw[ks][Ht] = *(const bf16x8*)&S[wo + row * 128 + (((ks * 4 + q) ^ (row & 7)) * 16)];
        }
#pragma unroll
        for (int Mt = 0; Mt < 4; Mt++) {
          const int row = waveM * 64 + Mt * 16 + fr;
          bx[ks][Mt] = *(const bf16x8*)&S[xo + row * 128 + (((ks * 4 + q) ^ (row & 7)) * 16)];
        }
      }
      if (kc < 7) {
        STAGE_XS(kc + 1);
        STAGE_W1(ht, kc + 1);
      }
      if (kc == 6) STAGE_W2(ht, 0);
      __builtin_amdgcn_s_barrier();
      asm volatile("s_waitcnt lgkmcnt(0)" ::: "memory");
      __builtin_amdgcn_sched_barrier(0);
      __builtin_amdgcn_s_setprio(1);
#pragma unroll
      for (int ks = 0; ks < 2; ks++)
#pragma unroll
        for (int Mt = 0; Mt < 4; Mt++)
#pragma unroll
          for (int Ht = 0; Ht < 2; Ht++)
            ha[Mt][Ht] = __builtin_amdgcn_mfma_f32_16x16x32_bf16(aw[ks][Ht], bx[ks][Mt],
                                                                 ha[Mt][Ht], 0, 0, 0);
      __builtin_amdgcn_s_setprio(0);
      if (kc == 6) asm volatile("s_waitcnt vmcnt(4)" ::: "memory");
      else         asm volatile("s_waitcnt vmcnt(0)" ::: "memory");
      __builtin_amdgcn_s_barrier();
    }

    // ================= h write: +b1, relu, pack, b64 into swizzled h =================
    {
      float b1v[8];
#pragma unroll
      for (int Ht = 0; Ht < 2; Ht++)
#pragma unroll
        for (int r = 0; r < 4; r++)
          b1v[Ht * 4 + r] = b1[ht * 128 + waveN * 32 + Ht * 16 + q * 4 + r];
#pragma unroll
      for (int Mt = 0; Mt < 4; Mt++) {
        const int M = waveM * 64 + Mt * 16 + fr;
        const int mb = HOF + M * 256;
        const int key = M & 7;
#pragma unroll
        for (int Ht = 0; Ht < 2; Ht++) {
          const int Hb = waveN * 32 + Ht * 16 + q * 4;
          const int slot = Hb >> 3;
          const int inslot = (Hb * 2) & 15;  // 8*(q&1)
          float v0 = fmaxf(ha[Mt][Ht][0] + b1v[Ht * 4 + 0], 0.f);
          float v1 = fmaxf(ha[Mt][Ht][1] + b1v[Ht * 4 + 1], 0.f);
          float v2 = fmaxf(ha[Mt][Ht][2] + b1v[Ht * 4 + 2], 0.f);
          float v3 = fmaxf(ha[Mt][Ht][3] + b1v[Ht * 4 + 3], 0.f);
          __hip_bfloat16 h0 = __float2bfloat16(v0), h1 = __float2bfloat16(v1);
          __hip_bfloat16 h2 = __float2bfloat16(v2), h3 = __float2bfloat16(v3);
          uint2 pk;
          pk.x = (unsigned)*(unsigned short*)&h0 | ((unsigned)*(unsigned short*)&h1 << 16);
          pk.y = (unsigned)*(unsigned short*)&h2 | ((unsigned)*(unsigned short*)&h3 << 16);
          *(uint2*)&S[mb + ((slot ^ key) * 16) + inslot] = pk;
          ha[Mt][Ht] = zero;  // reset for next ht
        }
      }
      asm volatile("s_waitcnt lgkmcnt(0)" ::: "memory");
      __builtin_amdgcn_s_barrier();
    }

    // ================= z-part: 4 chunks of BK=32 over this H-slice =================
    for (int zc = 0; zc < 4; ++zc) {
      const int zo = W2O + (zc & 1) * 32768;
      bf16x8 ah[4], bw[8];
#pragma unroll
      for (int Mt = 0; Mt < 4; Mt++) {
        const int M = waveM * 64 + Mt * 16 + fr;
        ah[Mt] = *(const bf16x8*)&S[HOF + M * 256 + (((zc * 4 + q) ^ (M & 7)) * 16)];
      }
#pragma unroll
      for (int Ft = 0; Ft < 8; Ft++) {
        const int row = waveN * 128 + Ft * 16 + fr;
        bw[Ft] = *(const bf16x8*)&S[zo + row * 64 + ((q ^ ((row >> 1) & 3)) * 16)];
      }
      if (zc < 3) {
        STAGE_W2(ht, zc + 1);
      } else if (ht < 15) {
        STAGE_XS(0);
        STAGE_W1(ht + 1, 0);
      }
      __builtin_amdgcn_s_barrier();
      asm volatile("s_waitcnt lgkmcnt(0)" ::: "memory");
      __builtin_amdgcn_sched_barrier(0);
      __builtin_amdgcn_s_setprio(1);
#pragma unroll
      for (int Mt = 0; Mt < 4; Mt++)
#pragma unroll
        for (int Ft = 0; Ft < 8; Ft++)
          za[Mt][Ft] = __builtin_amdgcn_mfma_f32_16x16x32_bf16(ah[Mt], bw[Ft], za[Mt][Ft], 0, 0, 0);
      __builtin_amdgcn_s_setprio(0);
      asm volatile("s_waitcnt vmcnt(0)" ::: "memory");
      __builtin_amdgcn_s_barrier();
    }
  }
#undef STAGE_XS
#undef STAGE_W1
#undef STAGE_W2

  // ================= epilogue: z = za + b2 + xs (skip), bf16 stores =================
  const int cn = fr;
  const int cm = q * 4;
  float bz[8];
#pragma unroll
  for (int Ft = 0; Ft < 8; Ft++) bz[Ft] = b2[waveN * 128 + Ft * 16 + cn];
#pragma unroll
  for (int Mt = 0; Mt < 4; Mt++) {
#pragma unroll
    for (int Ft = 0; Ft < 8; Ft++) {
      const size_t gn = waveN * 128 + Ft * 16 + cn;
#pragma unroll
      for (int r = 0; r < 4; r++) {
        const size_t gm = m0 + waveM * 64 + Mt * 16 + cm + r;
        float v = za[Mt][Ft][r] + bz[Ft] + __bfloat162float(xsb[gm * FF + gn]);
        Z[gm * FF + gn] = __float2bfloat16(v);
      }
    }
  }
}

// ---------------------------------------------------------------- final permute (pure gather)
__global__ __launch_bounds__(256) void permute_gather(const bf16* __restrict__ zp,
                                                      const unsigned* __restrict__ srt_pack,
                                                      float* __restrict__ out) {
  __shared__ __align__(16) unsigned short zr[4][FF];
  const int t = threadIdx.x;
  const int lane = t & 63;
  const int w = t >> 6;
  const size_t row = (size_t)blockIdx.x * 4 + w;

  *(uint4*)&zr[w][lane * 8] = *(const uint4*)(zp + row * FF + lane * 8);
  uint4 sv = *(const uint4*)(srt_pack + row * 256 + lane * 4);
  __syncthreads();

  unsigned idx[8] = {sv.x & 0xFFFFu, sv.x >> 16, sv.y & 0xFFFFu, sv.y >> 16,
                     sv.z & 0xFFFFu, sv.z >> 16, sv.w & 0xFFFFu, sv.w >> 16};
  float4 o0, o1;
#pragma unroll
  for (int r = 0; r < 8; r++) {
    float zf = __uint_as_float(((unsigned)zr[w][idx[r]]) << 16);
    ((r < 4) ? (&o0.x) : (&o1.x))[r & 3] = zf;
  }
  *(float4*)(out + row * FF + lane * 8) = o0;
  *(float4*)(out + row * FF + lane * 8 + 4) = o1;
}

// ---------------------------------------------------------------- launch
extern "C" void kernel_launch(void* const* d_in, const int* in_sizes, int n_in,
                              void* d_out, int out_size, void* d_ws, size_t ws_size,
                              hipStream_t stream) {
  const float* x  = (const float*)d_in[0];
  const float* W1 = (const float*)d_in[1];
  const float* b1 = (const float*)d_in[2];
  const float* W2 = (const float*)d_in[3];
  const float* b2 = (const float*)d_in[4];
  float* out = (float*)d_out;

  char* ws = (char*)d_ws;
  unsigned* xs  = (unsigned*)(ws);                           // 32 MiB bf16 xs (sorted domain)
  bf16*     xsb = (bf16*)(ws);
  unsigned* srt = (unsigned*)(ws + 33554432);                // 32 MiB u16 srt
  bf16* z   = (bf16*)(ws + 67108864);                        // 32 MiB bf16 z (sorted domain)
  bf16* W1b = (bf16*)(ws + 100663296);                       // 2 MiB
  bf16* W2b = (bf16*)(ws + 102760448);                       // 2 MiB

  cvt_pair<<<(HH * FF + 255) / 256, 256, 0, stream>>>(W1, W1b, W2, W2b, HH * FF);
  sort_rows_wave<<<M_ROWS / 4, 256, 0, stream>>>(x, xs, srt);
  // z = relu(xs @ W1^T + b1) @ W2^T + b2 + xs   -- single fused kernel, h stays on-chip
  fused_mlp<<<M_ROWS / 128, 512, 0, stream>>>(xsb, W1b, b1, W2b, b2, z);
  permute_gather<<<M_ROWS / 4, 256, 0, stream>>>(z, srt, out);
}

// Round 6
// 375.092 us; speedup vs baseline: 1.7005x; 1.7005x over previous
//
#include <hip/hip_runtime.h>
#include <hip/hip_bf16.h>

typedef __hip_bfloat16 bf16;
typedef __attribute__((ext_vector_type(8))) short bf16x8;   // 8 bf16 = 4 VGPRs (MFMA A/B frag)
typedef __attribute__((ext_vector_type(4))) float f32x4;    // MFMA C/D frag

#define ASYNC_CP16(gsrc, ldst)                                                              \
  __builtin_amdgcn_global_load_lds(                                                         \
      (const __attribute__((address_space(1))) unsigned int*)(gsrc),                        \
      (__attribute__((address_space(3))) unsigned int*)(ldst), 16, 0, 0)

#define BB 32
#define NN 1024
#define FF 512
#define HH 2048
#define M_ROWS (BB * NN)  // 32768

// ---------------------------------------------------------------- weight casts (fused)
__global__ __launch_bounds__(256) void cvt_pair(const float* __restrict__ a, bf16* __restrict__ da,
                                                const float* __restrict__ b, bf16* __restrict__ db,
                                                int n) {
  int i = blockIdx.x * 256 + threadIdx.x;
  if (i < n) {
    da[i] = __float2bfloat16(a[i]);
    db[i] = __float2bfloat16(b[i]);
  }
}

// ---------------------------------------------------------------- cross-lane xor via LDS crossbar
template <int IMM>
__device__ __forceinline__ unsigned long long swz64(unsigned long long k) {
  int lo = __builtin_amdgcn_ds_swizzle((int)(unsigned)k, IMM);
  int hi = __builtin_amdgcn_ds_swizzle((int)(unsigned)(k >> 32), IMM);
  return (((unsigned long long)(unsigned)hi) << 32) | (unsigned)lo;
}

// ---------------------------------------------------------------- stable argsort per row
// (unchanged from R3/R4 passing version)
__global__ __launch_bounds__(256) void sort_rows_wave(const float* __restrict__ x,
                                                      unsigned* __restrict__ xs_pack,
                                                      unsigned* __restrict__ srt_pack) {
  __shared__ __align__(16) unsigned short scatx[4 * FF];
  const int t = threadIdx.x;
  const int lane = t & 63;
  const int w = t >> 6;
  const size_t row = (size_t)blockIdx.x * 4 + w;
  const float* xr = x + row * FF;

  float4 v0 = *(const float4*)(xr + lane * 8);
  float4 v1 = *(const float4*)(xr + lane * 8 + 4);
  float vals[8] = {v0.x, v0.y, v0.z, v0.w, v1.x, v1.y, v1.z, v1.w};

  unsigned long long key[8];
#pragma unroll
  for (int r = 0; r < 8; r++) {
    unsigned u = __float_as_uint(vals[r]);
    unsigned s = u ^ ((unsigned)((int)u >> 31) | 0x80000000u);  // monotone fp32->u32
    key[r] = ((unsigned long long)s << 32) | (unsigned)(lane * 8 + r);
  }

#pragma unroll
  for (int k = 2; k <= 512; k <<= 1) {
#pragma unroll
    for (int j = k >> 1; j > 0; j >>= 1) {
      if (j >= 8) {
        const int d = j >> 3;
        unsigned long long o[8];
#pragma unroll
        for (int r = 0; r < 8; r++) {
          if (d == 1)       o[r] = swz64<0x041F>(key[r]);
          else if (d == 2)  o[r] = swz64<0x081F>(key[r]);
          else if (d == 4)  o[r] = swz64<0x101F>(key[r]);
          else if (d == 8)  o[r] = swz64<0x201F>(key[r]);
          else if (d == 16) o[r] = swz64<0x401F>(key[r]);
          else              o[r] = __shfl_xor(key[r], 32, 64);
        }
        bool asc = (((lane * 8) & k) == 0);
        bool lower = ((lane & d) == 0);
        bool keep = (asc == lower);
#pragma unroll
        for (int r = 0; r < 8; r++) {
          bool mine = key[r] < o[r];
          key[r] = (mine == keep) ? key[r] : o[r];
        }
      } else {
#pragma unroll
        for (int r = 0; r < 8; r++) {
          if ((r & j) == 0) {
            const int a = r, b = r | j;
            bool asc = (((lane * 8 + a) & k) == 0);
            unsigned long long ka = key[a], kb = key[b];
            bool sw = ((ka > kb) == asc);
            key[a] = sw ? kb : ka;
            key[b] = sw ? ka : kb;
          }
        }
      }
    }
  }

  const int base = w * FF;
  unsigned j8[8];
#pragma unroll
  for (int r = 0; r < 8; r++) {
    j8[r] = (unsigned)key[r] & 0xFFFFu;
    __hip_bfloat16 hb = __float2bfloat16(vals[r]);
    scatx[base + j8[r]] = *(unsigned short*)&hb;
  }

  uint4 so;
  so.x = j8[0] | (j8[1] << 16);
  so.y = j8[2] | (j8[3] << 16);
  so.z = j8[4] | (j8[5] << 16);
  so.w = j8[6] | (j8[7] << 16);
  *(uint4*)(srt_pack + row * 256 + lane * 4) = so;

  __syncthreads();
  uint4 xo = *(const uint4*)&scatx[base + lane * 8];
  *(uint4*)(xs_pack + row * 256 + lane * 4) = xo;
}

// ---------------------------------------------------------------- 8-phase 256x256 GEMM
// (T1 XCD remap + T2 swizzle + T3 phases + T4 DEEPENED counted vmcnt + T5 setprio)
// R6 change vs R4: stage the ENTIRE next tile during P1/P2 (slots (2kt+2)&3,(2kt+3)&3 are
// free for all of tile kt in the 4-half-slot LDS ring), doubling in-flight loads 4->8/wave
// and giving P1-consumed data 4 phases (~2500 cyc) of lead instead of 2.
// Per-wave vmcnt ledger (in-order completion):
//   prologue: 8 issued, vmcnt(4) -> A/B(0,0) done, 4 left.
//   steady end-P2: 4 old + 8 new = 12 -> vmcnt(8) completes A/B(kt,1) for P3/P4.
//   steady end-P4: 8 -> vmcnt(4) completes A/B(kt+1,0) for next P1.
//   last tile: end-P2 vmcnt(0) (drain old 4); no P4 wait.
// NO __syncthreads anywhere (it would drain vmcnt(0) and kill the pipeline).
template <int RELU, int ADDX, int K, int N>
__global__ __launch_bounds__(512, 2) void gemm8p(const bf16* __restrict__ A,
                                                 const bf16* __restrict__ Bw,
                                                 const float* __restrict__ bias,
                                                 const bf16* __restrict__ xs_add,
                                                 bf16* __restrict__ C) {
  __shared__ __align__(16) bf16 S[65536];  // 128 KiB
  const int t = threadIdx.x;
  const int lane = t & 63, wave = t >> 6;
  const int waveM = wave >> 2, waveN = wave & 3;

  constexpr int GY = N / 256;                       // blocks in the N dimension
  static_assert((M_ROWS / 256) % 8 == 0, "x-chunking assumes 16 x per XCD");
  const int g = (int)blockIdx.x;
  const int q = g >> 3;
  const size_t mBase = (size_t)((g & 7) * ((M_ROWS / 256) / 8) + q / GY) * 256;
  const size_t nBase = (size_t)(q % GY) * 256;

  // staging: thread covers 16B slot s = t (+512 for second load); row = s>>2, pre-swizzled col
  const int srow = t >> 2;                        // 0..127 (second load: +128)
  const int sclog = (t & 3) ^ ((t >> 3) & 3);     // inverse-swizzled source col slot
  const bf16* Asrc0 = A + (mBase + srow) * (size_t)K + sclog * 8;
  const bf16* Bsrc0 = Bw + (nBase + srow) * (size_t)K + sclog * 8;
  const int sdA = wave * 512;                     // LDS dest (elements), + region base
  const int sdB = 32768 + wave * 512;

  // fragment reads: row = (tile-row) + fr, swizzled 16B slot = (lane>>4) ^ ((fr>>1)&3)
  const int fr = lane & 15;
  const int swz8 = ((lane >> 4) ^ ((lane >> 1) & 3)) * 8;
  const int aRd = (waveM * 128 + fr) * 32 + swz8;           // + region + mh*2048 + i*512
  const int bRd = 32768 + (waveN * 64 + fr) * 32 + swz8;    // + region(buf,ks) + nt*512

#define STAGE_A(tt, ks)                                           \
  do {                                                            \
    const int rb_ = (((tt) & 1) * 2 + (ks)) * 8192 + sdA;         \
    const bf16* g_ = Asrc0 + (size_t)(tt) * 64 + (ks) * 32;       \
    ASYNC_CP16(g_, &S[rb_]);                                      \
    ASYNC_CP16(g_ + (size_t)128 * K, &S[rb_ + 4096]);             \
  } while (0)
#define STAGE_B(tt, ks)                                           \
  do {                                                            \
    const int rb_ = (((tt) & 1) * 2 + (ks)) * 8192 + sdB;         \
    const bf16* g_ = Bsrc0 + (size_t)(tt) * 64 + (ks) * 32;       \
    ASYNC_CP16(g_, &S[rb_]);                                      \
    ASYNC_CP16(g_ + (size_t)128 * K, &S[rb_ + 4096]);             \
  } while (0)

  f32x4 acc[8][4];
  f32x4 zero = {0.f, 0.f, 0.f, 0.f};
#pragma unroll
  for (int i = 0; i < 8; i++)
#pragma unroll
    for (int j = 0; j < 4; j++) acc[i][j] = zero;

  // prologue: stage tile 0 fully (8 loads); complete first K-half, keep second in flight
  STAGE_A(0, 0);
  STAGE_B(0, 0);
  STAGE_A(0, 1);
  STAGE_B(0, 1);
  asm volatile("s_waitcnt vmcnt(4)" ::: "memory");
  __builtin_amdgcn_s_barrier();

  const int NT = K / 64;
  for (int kt = 0; kt < NT; ++kt) {
    const int buf = kt & 1;
    const bool pf = (kt + 1 < NT);
    bf16x8 af[4], bq[4];

    // ---- P1: (mh=0, ks=0) — stage next tile's first K-half
    {
      const int rg = buf * 16384;
#pragma unroll
      for (int i = 0; i < 4; i++) af[i] = *(const bf16x8*)&S[rg + aRd + i * 512];
#pragma unroll
      for (int n = 0; n < 4; n++) bq[n] = *(const bf16x8*)&S[rg + bRd + n * 512];
      if (pf) {
        STAGE_A(kt + 1, 0);
        STAGE_B(kt + 1, 0);
      }
      __builtin_amdgcn_s_barrier();
      asm volatile("s_waitcnt lgkmcnt(0)" ::: "memory");
      __builtin_amdgcn_sched_barrier(0);
      __builtin_amdgcn_s_setprio(1);
#pragma unroll
      for (int i = 0; i < 4; i++)
#pragma unroll
        for (int n = 0; n < 4; n++)
          acc[i][n] = __builtin_amdgcn_mfma_f32_16x16x32_bf16(af[i], bq[n], acc[i][n], 0, 0, 0);
      __builtin_amdgcn_s_setprio(0);
      __builtin_amdgcn_s_barrier();
    }
    // ---- P2: (mh=1, ks=0) — reuse bq; stage next tile's second K-half
    {
      const int rg = buf * 16384;
#pragma unroll
      for (int i = 0; i < 4; i++) af[i] = *(const bf16x8*)&S[rg + aRd + 2048 + i * 512];
      if (pf) {
        STAGE_A(kt + 1, 1);
        STAGE_B(kt + 1, 1);
      }
      __builtin_amdgcn_s_barrier();
      asm volatile("s_waitcnt lgkmcnt(0)" ::: "memory");
      __builtin_amdgcn_sched_barrier(0);
      __builtin_amdgcn_s_setprio(1);
#pragma unroll
      for (int i = 0; i < 4; i++)
#pragma unroll
        for (int n = 0; n < 4; n++)
          acc[4 + i][n] = __builtin_amdgcn_mfma_f32_16x16x32_bf16(af[i], bq[n], acc[4 + i][n], 0, 0, 0);
      __builtin_amdgcn_s_setprio(0);
      // completes A/B(kt,1) needed by P3/P4; leaves next tile's 8 loads in flight
      if (pf) asm volatile("s_waitcnt vmcnt(8)" ::: "memory");
      else    asm volatile("s_waitcnt vmcnt(0)" ::: "memory");
      __builtin_amdgcn_s_barrier();
    }
    // ---- P3: (mh=0, ks=1)
    {
      const int rg = buf * 16384 + 8192;
#pragma unroll
      for (int i = 0; i < 4; i++) af[i] = *(const bf16x8*)&S[rg + aRd + i * 512];
#pragma unroll
      for (int n = 0; n < 4; n++) bq[n] = *(const bf16x8*)&S[rg + bRd + n * 512];
      __builtin_amdgcn_s_barrier();
      asm volatile("s_waitcnt lgkmcnt(0)" ::: "memory");
      __builtin_amdgcn_sched_barrier(0);
      __builtin_amdgcn_s_setprio(1);
#pragma unroll
      for (int i = 0; i < 4; i++)
#pragma unroll
        for (int n = 0; n < 4; n++)
          acc[i][n] = __builtin_amdgcn_mfma_f32_16x16x32_bf16(af[i], bq[n], acc[i][n], 0, 0, 0);
      __builtin_amdgcn_s_setprio(0);
      __builtin_amdgcn_s_barrier();
    }
    // ---- P4: (mh=1, ks=1)
    {
      const int rg = buf * 16384 + 8192;
#pragma unroll
      for (int i = 0; i < 4; i++) af[i] = *(const bf16x8*)&S[rg + aRd + 2048 + i * 512];
      __builtin_amdgcn_s_barrier();
      asm volatile("s_waitcnt lgkmcnt(0)" ::: "memory");
      __builtin_amdgcn_sched_barrier(0);
      __builtin_amdgcn_s_setprio(1);
#pragma unroll
      for (int i = 0; i < 4; i++)
#pragma unroll
        for (int n = 0; n < 4; n++)
          acc[4 + i][n] = __builtin_amdgcn_mfma_f32_16x16x32_bf16(af[i], bq[n], acc[4 + i][n], 0, 0, 0);
      __builtin_amdgcn_s_setprio(0);
      // completes A/B(kt+1,0) needed by next P1; leaves A/B(kt+1,1) in flight
      if (pf) asm volatile("s_waitcnt vmcnt(4)" ::: "memory");
      __builtin_amdgcn_s_barrier();
    }
  }
#undef STAGE_A
#undef STAGE_B

  // epilogue: C/D layout col=lane&15, row=(lane>>4)*4+reg (harness-verified mapping)
  const int cn = lane & 15;
  const int cm = (lane >> 4) * 4;
  float b4[4];
#pragma unroll
  for (int n = 0; n < 4; n++) b4[n] = bias[nBase + waveN * 64 + n * 16 + cn];
#pragma unroll
  for (int mt = 0; mt < 8; mt++) {
#pragma unroll
    for (int n = 0; n < 4; n++) {
      size_t gn = nBase + waveN * 64 + n * 16 + cn;
#pragma unroll
      for (int r = 0; r < 4; r++) {
        size_t gm = mBase + waveM * 128 + mt * 16 + cm + r;
        float v = acc[mt][n][r] + b4[n];
        if (RELU) v = fmaxf(v, 0.f);
        if (ADDX) v += __bfloat162float(xs_add[gm * (size_t)N + gn]);
        C[gm * (size_t)N + gn] = __float2bfloat16(v);
      }
    }
  }
}

// ---------------------------------------------------------------- final permute (pure gather)
__global__ __launch_bounds__(256) void permute_gather(const bf16* __restrict__ zp,
                                                      const unsigned* __restrict__ srt_pack,
                                                      float* __restrict__ out) {
  __shared__ __align__(16) unsigned short zr[4][FF];
  const int t = threadIdx.x;
  const int lane = t & 63;
  const int w = t >> 6;
  const size_t row = (size_t)blockIdx.x * 4 + w;

  *(uint4*)&zr[w][lane * 8] = *(const uint4*)(zp + row * FF + lane * 8);
  uint4 sv = *(const uint4*)(srt_pack + row * 256 + lane * 4);
  __syncthreads();

  unsigned idx[8] = {sv.x & 0xFFFFu, sv.x >> 16, sv.y & 0xFFFFu, sv.y >> 16,
                     sv.z & 0xFFFFu, sv.z >> 16, sv.w & 0xFFFFu, sv.w >> 16};
  float4 o0, o1;
#pragma unroll
  for (int r = 0; r < 8; r++) {
    float zf = __uint_as_float(((unsigned)zr[w][idx[r]]) << 16);
    ((r < 4) ? (&o0.x) : (&o1.x))[r & 3] = zf;
  }
  *(float4*)(out + row * FF + lane * 8) = o0;
  *(float4*)(out + row * FF + lane * 8 + 4) = o1;
}

// ---------------------------------------------------------------- launch
extern "C" void kernel_launch(void* const* d_in, const int* in_sizes, int n_in,
                              void* d_out, int out_size, void* d_ws, size_t ws_size,
                              hipStream_t stream) {
  const float* x  = (const float*)d_in[0];
  const float* W1 = (const float*)d_in[1];
  const float* b1 = (const float*)d_in[2];
  const float* W2 = (const float*)d_in[3];
  const float* b2 = (const float*)d_in[4];
  float* out = (float*)d_out;

  char* ws = (char*)d_ws;
  // z aliases xs ([M][512] bf16, identical layout): gemm2 reads xs(gm,gn) then writes
  // z(gm,gn) from the SAME thread, tiles disjoint across blocks -> safe.
  unsigned* xs  = (unsigned*)(ws);                           // 32 MiB bf16 xs
  bf16*     xsb = (bf16*)(ws);
  bf16*     z   = (bf16*)(ws);                               // aliases xs
  unsigned* srt = (unsigned*)(ws + 33554432);                // 32 MiB u16 srt
  bf16* h   = (bf16*)(ws + 67108864);                        // 128 MiB
  bf16* W1b = (bf16*)(ws + 201326592);                       // 2 MiB
  bf16* W2b = (bf16*)(ws + 203423744);                       // 2 MiB

  cvt_pair<<<(HH * FF + 255) / 256, 256, 0, stream>>>(W1, W1b, W2, W2b, HH * FF);
  sort_rows_wave<<<M_ROWS / 4, 256, 0, stream>>>(x, xs, srt);
  // h = relu(xs @ W1^T + b1): M=32768, K=512, N=2048  (1D grid, XCD-chunked remap inside)
  gemm8p<1, 0, FF, HH><<<(M_ROWS / 256) * (HH / 256), 512, 0, stream>>>(xsb, W1b, b1, nullptr, h);
  // z = h @ W2^T + b2 + xs: M=32768, K=2048, N=512  (skip fused, sorted domain)
  gemm8p<0, 1, HH, FF><<<(M_ROWS / 256) * (FF / 256), 512, 0, stream>>>(h, W2b, b2, xsb, z);
  permute_gather<<<M_ROWS / 4, 256, 0, stream>>>(z, srt, out);
}

// Round 7
// 362.311 us; speedup vs baseline: 1.7604x; 1.0353x over previous
//
#include <hip/hip_runtime.h>
#include <hip/hip_bf16.h>

typedef __hip_bfloat16 bf16;
typedef __attribute__((ext_vector_type(8))) short bf16x8;   // 8 bf16 = 4 VGPRs (MFMA A/B frag)
typedef __attribute__((ext_vector_type(4))) float f32x4;    // MFMA C/D frag

#define ASYNC_CP16(gsrc, ldst)                                                              \
  __builtin_amdgcn_global_load_lds(                                                         \
      (const __attribute__((address_space(1))) unsigned int*)(gsrc),                        \
      (__attribute__((address_space(3))) unsigned int*)(ldst), 16, 0, 0)

#define BB 32
#define NN 1024
#define FF 512
#define HH 2048
#define M_ROWS (BB * NN)  // 32768

// ---------------------------------------------------------------- weight casts (fused)
__global__ __launch_bounds__(256) void cvt_pair(const float* __restrict__ a, bf16* __restrict__ da,
                                                const float* __restrict__ b, bf16* __restrict__ db,
                                                int n) {
  int i = blockIdx.x * 256 + threadIdx.x;
  if (i < n) {
    da[i] = __float2bfloat16(a[i]);
    db[i] = __float2bfloat16(b[i]);
  }
}

// ---------------------------------------------------------------- cross-lane xor via LDS crossbar
template <int IMM>
__device__ __forceinline__ unsigned long long swz64(unsigned long long k) {
  int lo = __builtin_amdgcn_ds_swizzle((int)(unsigned)k, IMM);
  int hi = __builtin_amdgcn_ds_swizzle((int)(unsigned)(k >> 32), IMM);
  return (((unsigned long long)(unsigned)hi) << 32) | (unsigned)lo;
}

// ---------------------------------------------------------------- stable argsort per row
// (unchanged from R3/R4 passing version)
__global__ __launch_bounds__(256) void sort_rows_wave(const float* __restrict__ x,
                                                      unsigned* __restrict__ xs_pack,
                                                      unsigned* __restrict__ srt_pack) {
  __shared__ __align__(16) unsigned short scatx[4 * FF];
  const int t = threadIdx.x;
  const int lane = t & 63;
  const int w = t >> 6;
  const size_t row = (size_t)blockIdx.x * 4 + w;
  const float* xr = x + row * FF;

  float4 v0 = *(const float4*)(xr + lane * 8);
  float4 v1 = *(const float4*)(xr + lane * 8 + 4);
  float vals[8] = {v0.x, v0.y, v0.z, v0.w, v1.x, v1.y, v1.z, v1.w};

  unsigned long long key[8];
#pragma unroll
  for (int r = 0; r < 8; r++) {
    unsigned u = __float_as_uint(vals[r]);
    unsigned s = u ^ ((unsigned)((int)u >> 31) | 0x80000000u);  // monotone fp32->u32
    key[r] = ((unsigned long long)s << 32) | (unsigned)(lane * 8 + r);
  }

#pragma unroll
  for (int k = 2; k <= 512; k <<= 1) {
#pragma unroll
    for (int j = k >> 1; j > 0; j >>= 1) {
      if (j >= 8) {
        const int d = j >> 3;
        unsigned long long o[8];
#pragma unroll
        for (int r = 0; r < 8; r++) {
          if (d == 1)       o[r] = swz64<0x041F>(key[r]);
          else if (d == 2)  o[r] = swz64<0x081F>(key[r]);
          else if (d == 4)  o[r] = swz64<0x101F>(key[r]);
          else if (d == 8)  o[r] = swz64<0x201F>(key[r]);
          else if (d == 16) o[r] = swz64<0x401F>(key[r]);
          else              o[r] = __shfl_xor(key[r], 32, 64);
        }
        bool asc = (((lane * 8) & k) == 0);
        bool lower = ((lane & d) == 0);
        bool keep = (asc == lower);
#pragma unroll
        for (int r = 0; r < 8; r++) {
          bool mine = key[r] < o[r];
          key[r] = (mine == keep) ? key[r] : o[r];
        }
      } else {
#pragma unroll
        for (int r = 0; r < 8; r++) {
          if ((r & j) == 0) {
            const int a = r, b = r | j;
            bool asc = (((lane * 8 + a) & k) == 0);
            unsigned long long ka = key[a], kb = key[b];
            bool sw = ((ka > kb) == asc);
            key[a] = sw ? kb : ka;
            key[b] = sw ? ka : kb;
          }
        }
      }
    }
  }

  const int base = w * FF;
  unsigned j8[8];
#pragma unroll
  for (int r = 0; r < 8; r++) {
    j8[r] = (unsigned)key[r] & 0xFFFFu;
    __hip_bfloat16 hb = __float2bfloat16(vals[r]);
    scatx[base + j8[r]] = *(unsigned short*)&hb;
  }

  uint4 so;
  so.x = j8[0] | (j8[1] << 16);
  so.y = j8[2] | (j8[3] << 16);
  so.z = j8[4] | (j8[5] << 16);
  so.w = j8[6] | (j8[7] << 16);
  *(uint4*)(srt_pack + row * 256 + lane * 4) = so;

  __syncthreads();
  uint4 xo = *(const uint4*)&scatx[base + lane * 8];
  *(uint4*)(xs_pack + row * 256 + lane * 4) = xo;
}

// ---------------------------------------------------------------- 8-phase 256x256 GEMM
// (T1 XCD remap + T2 swizzle + T3 phases + T4 counted vmcnt R4-EXACT + T5 setprio)
// K-loop schedule is the R4-verified one: stages spread evenly P1..P4 (A0,B0,A1,B1 of tile
// kt+1), vmcnt(4) only at end-P2/end-P4. R6's bunched 2-tile prefetch regressed (m196's
// "coarse phase-split hurts") and is reverted.
// R7 NEW: LDS-transpose epilogue. After the K-loop the 128 KiB LDS is dead = exactly one
// 256x256 bf16 C-tile. acc -> LDS (bf16, 16B-slot XOR row&7), barrier, then 16 coalesced
// b128 stores/thread (512 B contiguous per half-wave). ADDX reads xs as coalesced uint4 and
// adds in-register (one extra bf16 rounding, margin-safe). Replaces 32 scalar 2B stores +
// (gemm2) 32 scalar 2B gathers per thread.
template <int RELU, int ADDX, int K, int N>
__global__ __launch_bounds__(512, 2) void gemm8p(const bf16* __restrict__ A,
                                                 const bf16* __restrict__ Bw,
                                                 const float* __restrict__ bias,
                                                 const bf16* __restrict__ xs_add,
                                                 bf16* __restrict__ C) {
  __shared__ __align__(16) bf16 S[65536];  // 128 KiB
  const int t = threadIdx.x;
  const int lane = t & 63, wave = t >> 6;
  const int waveM = wave >> 2, waveN = wave & 3;

  constexpr int GY = N / 256;                       // blocks in the N dimension
  static_assert((M_ROWS / 256) % 8 == 0, "x-chunking assumes 16 x per XCD");
  const int g = (int)blockIdx.x;
  const int q = g >> 3;
  const size_t mBase = (size_t)((g & 7) * ((M_ROWS / 256) / 8) + q / GY) * 256;
  const size_t nBase = (size_t)(q % GY) * 256;

  // staging: thread covers 16B slot s = t (+512 for second load); row = s>>2, pre-swizzled col
  const int srow = t >> 2;                        // 0..127 (second load: +128)
  const int sclog = (t & 3) ^ ((t >> 3) & 3);     // inverse-swizzled source col slot
  const bf16* Asrc0 = A + (mBase + srow) * (size_t)K + sclog * 8;
  const bf16* Bsrc0 = Bw + (nBase + srow) * (size_t)K + sclog * 8;
  const int sdA = wave * 512;                     // LDS dest (elements), + region base
  const int sdB = 32768 + wave * 512;

  // fragment reads: row = (tile-row) + fr, swizzled 16B slot = (lane>>4) ^ ((fr>>1)&3)
  const int fr = lane & 15;
  const int swz8 = ((lane >> 4) ^ ((lane >> 1) & 3)) * 8;
  const int aRd = (waveM * 128 + fr) * 32 + swz8;           // + region + mh*2048 + i*512
  const int bRd = 32768 + (waveN * 64 + fr) * 32 + swz8;    // + region(buf,ks) + nt*512

#define STAGE_A(tt, ks)                                           \
  do {                                                            \
    const int rb_ = (((tt) & 1) * 2 + (ks)) * 8192 + sdA;         \
    const bf16* g_ = Asrc0 + (size_t)(tt) * 64 + (ks) * 32;       \
    ASYNC_CP16(g_, &S[rb_]);                                      \
    ASYNC_CP16(g_ + (size_t)128 * K, &S[rb_ + 4096]);             \
  } while (0)
#define STAGE_B(tt, ks)                                           \
  do {                                                            \
    const int rb_ = (((tt) & 1) * 2 + (ks)) * 8192 + sdB;         \
    const bf16* g_ = Bsrc0 + (size_t)(tt) * 64 + (ks) * 32;       \
    ASYNC_CP16(g_, &S[rb_]);                                      \
    ASYNC_CP16(g_ + (size_t)128 * K, &S[rb_ + 4096]);             \
  } while (0)

  f32x4 acc[8][4];
  f32x4 zero = {0.f, 0.f, 0.f, 0.f};
#pragma unroll
  for (int i = 0; i < 8; i++)
#pragma unroll
    for (int j = 0; j < 4; j++) acc[i][j] = zero;

  // prologue: stage tile 0 fully; k0 halves guaranteed, k1 halves stay in flight
  STAGE_A(0, 0);
  STAGE_B(0, 0);
  STAGE_A(0, 1);
  STAGE_B(0, 1);
  asm volatile("s_waitcnt vmcnt(4)" ::: "memory");
  __builtin_amdgcn_s_barrier();

  const int NT = K / 64;
  for (int kt = 0; kt < NT; ++kt) {
    const int buf = kt & 1;
    const bool pf = (kt + 1 < NT);
    bf16x8 af[4], bq[4];

    // ---- P1: (mh=0, ks=0)
    {
      const int rg = buf * 16384;
#pragma unroll
      for (int i = 0; i < 4; i++) af[i] = *(const bf16x8*)&S[rg + aRd + i * 512];
#pragma unroll
      for (int n = 0; n < 4; n++) bq[n] = *(const bf16x8*)&S[rg + bRd + n * 512];
      if (pf) STAGE_A(kt + 1, 0);
      __builtin_amdgcn_s_barrier();
      asm volatile("s_waitcnt lgkmcnt(0)" ::: "memory");
      __builtin_amdgcn_sched_barrier(0);
      __builtin_amdgcn_s_setprio(1);
#pragma unroll
      for (int i = 0; i < 4; i++)
#pragma unroll
        for (int n = 0; n < 4; n++)
          acc[i][n] = __builtin_amdgcn_mfma_f32_16x16x32_bf16(af[i], bq[n], acc[i][n], 0, 0, 0);
      __builtin_amdgcn_s_setprio(0);
      __builtin_amdgcn_s_barrier();
    }
    // ---- P2: (mh=1, ks=0) — reuse bq
    {
      const int rg = buf * 16384;
#pragma unroll
      for (int i = 0; i < 4; i++) af[i] = *(const bf16x8*)&S[rg + aRd + 2048 + i * 512];
      if (pf) STAGE_B(kt + 1, 0);
      __builtin_amdgcn_s_barrier();
      asm volatile("s_waitcnt lgkmcnt(0)" ::: "memory");
      __builtin_amdgcn_sched_barrier(0);
      __builtin_amdgcn_s_setprio(1);
#pragma unroll
      for (int i = 0; i < 4; i++)
#pragma unroll
        for (int n = 0; n < 4; n++)
          acc[4 + i][n] = __builtin_amdgcn_mfma_f32_16x16x32_bf16(af[i], bq[n], acc[4 + i][n], 0, 0, 0);
      __builtin_amdgcn_s_setprio(0);
      if (pf) asm volatile("s_waitcnt vmcnt(4)" ::: "memory");
      else    asm volatile("s_waitcnt vmcnt(0)" ::: "memory");
      __builtin_amdgcn_s_barrier();
    }
    // ---- P3: (mh=0, ks=1)
    {
      const int rg = buf * 16384 + 8192;
#pragma unroll
      for (int i = 0; i < 4; i++) af[i] = *(const bf16x8*)&S[rg + aRd + i * 512];
#pragma unroll
      for (int n = 0; n < 4; n++) bq[n] = *(const bf16x8*)&S[rg + bRd + n * 512];
      if (pf) STAGE_A(kt + 1, 1);
      __builtin_amdgcn_s_barrier();
      asm volatile("s_waitcnt lgkmcnt(0)" ::: "memory");
      __builtin_amdgcn_sched_barrier(0);
      __builtin_amdgcn_s_setprio(1);
#pragma unroll
      for (int i = 0; i < 4; i++)
#pragma unroll
        for (int n = 0; n < 4; n++)
          acc[i][n] = __builtin_amdgcn_mfma_f32_16x16x32_bf16(af[i], bq[n], acc[i][n], 0, 0, 0);
      __builtin_amdgcn_s_setprio(0);
      __builtin_amdgcn_s_barrier();
    }
    // ---- P4: (mh=1, ks=1)
    {
      const int rg = buf * 16384 + 8192;
#pragma unroll
      for (int i = 0; i < 4; i++) af[i] = *(const bf16x8*)&S[rg + aRd + 2048 + i * 512];
      if (pf) STAGE_B(kt + 1, 1);
      __builtin_amdgcn_s_barrier();
      asm volatile("s_waitcnt lgkmcnt(0)" ::: "memory");
      __builtin_amdgcn_sched_barrier(0);
      __builtin_amdgcn_s_setprio(1);
#pragma unroll
      for (int i = 0; i < 4; i++)
#pragma unroll
        for (int n = 0; n < 4; n++)
          acc[4 + i][n] = __builtin_amdgcn_mfma_f32_16x16x32_bf16(af[i], bq[n], acc[4 + i][n], 0, 0, 0);
      __builtin_amdgcn_s_setprio(0);
      if (pf) asm volatile("s_waitcnt vmcnt(4)" ::: "memory");
      __builtin_amdgcn_s_barrier();
    }
  }
#undef STAGE_A
#undef STAGE_B

  // ---- epilogue v2: acc -> LDS C-tile (bf16, XOR-swizzled) -> coalesced b128 stores.
  // After the final barrier all K-loop LDS reads are done -> safe to overwrite S.
  // C/D frag layout: col = lane&15, row = (lane>>4)*4 + reg (harness-verified).
  {
    const int cn = lane & 15;
    const int cm = (lane >> 4) * 4;
    float b4[4];
#pragma unroll
    for (int n = 0; n < 4; n++) b4[n] = bias[nBase + waveN * 64 + n * 16 + cn];
    unsigned short* Ct = (unsigned short*)S;  // 256 rows x 512 B (256 bf16 cols) = 128 KiB
#pragma unroll
    for (int mt = 0; mt < 8; mt++) {
      const int rowBase = waveM * 128 + mt * 16 + cm;
#pragma unroll
      for (int n = 0; n < 4; n++) {
        const int col = waveN * 64 + n * 16 + cn;
#pragma unroll
        for (int r = 0; r < 4; r++) {
          const int row = rowBase + r;
          float v = acc[mt][n][r] + b4[n];
          if (RELU) v = fmaxf(v, 0.f);
          __hip_bfloat16 hv = __float2bfloat16(v);
          // 16B-slot XOR swizzle by row&7 (write banks spread; readback applies same XOR)
          const int slot = ((col >> 3) ^ (row & 7));
          const int byteA = row * 512 + (slot << 4) + ((col * 2) & 15);
          Ct[byteA >> 1] = *(unsigned short*)&hv;
        }
      }
    }
    asm volatile("s_waitcnt lgkmcnt(0)" ::: "memory");
    __builtin_amdgcn_s_barrier();
#pragma unroll
    for (int i = 0; i < 16; i++) {
      const int idx = i * 8192 + t * 16;  // linear byte index in [256][512B]
      const int row = idx >> 9;
      const int cb = idx & 511;           // column-byte, 16-aligned
      const int pb = row * 512 + ((((cb >> 4) ^ (row & 7)) << 4));
      uint4 pk = *(const uint4*)((const unsigned char*)S + pb);
      const size_t gOff = (mBase + row) * (size_t)N + nBase + (cb >> 1);
      if (ADDX) {
        uint4 xa = *(const uint4*)&xs_add[gOff];
        unsigned pw[4] = {pk.x, pk.y, pk.z, pk.w};
        unsigned xw[4] = {xa.x, xa.y, xa.z, xa.w};
#pragma unroll
        for (int wd = 0; wd < 4; wd++) {
          unsigned a = pw[wd], b = xw[wd];
          float lo = __uint_as_float((a & 0xFFFFu) << 16) + __uint_as_float((b & 0xFFFFu) << 16);
          float hi = __uint_as_float(a & 0xFFFF0000u) + __uint_as_float(b & 0xFFFF0000u);
          __hip_bfloat16 l = __float2bfloat16(lo), h2 = __float2bfloat16(hi);
          pw[wd] = (unsigned)*(unsigned short*)&l | ((unsigned)*(unsigned short*)&h2 << 16);
        }
        pk.x = pw[0]; pk.y = pw[1]; pk.z = pw[2]; pk.w = pw[3];
      }
      *(uint4*)&C[gOff] = pk;
    }
  }
}

// ---------------------------------------------------------------- final permute (pure gather)
__global__ __launch_bounds__(256) void permute_gather(const bf16* __restrict__ zp,
                                                      const unsigned* __restrict__ srt_pack,
                                                      float* __restrict__ out) {
  __shared__ __align__(16) unsigned short zr[4][FF];
  const int t = threadIdx.x;
  const int lane = t & 63;
  const int w = t >> 6;
  const size_t row = (size_t)blockIdx.x * 4 + w;

  *(uint4*)&zr[w][lane * 8] = *(const uint4*)(zp + row * FF + lane * 8);
  uint4 sv = *(const uint4*)(srt_pack + row * 256 + lane * 4);
  __syncthreads();

  unsigned idx[8] = {sv.x & 0xFFFFu, sv.x >> 16, sv.y & 0xFFFFu, sv.y >> 16,
                     sv.z & 0xFFFFu, sv.z >> 16, sv.w & 0xFFFFu, sv.w >> 16};
  float4 o0, o1;
#pragma unroll
  for (int r = 0; r < 8; r++) {
    float zf = __uint_as_float(((unsigned)zr[w][idx[r]]) << 16);
    ((r < 4) ? (&o0.x) : (&o1.x))[r & 3] = zf;
  }
  *(float4*)(out + row * FF + lane * 8) = o0;
  *(float4*)(out + row * FF + lane * 8 + 4) = o1;
}

// ---------------------------------------------------------------- launch
extern "C" void kernel_launch(void* const* d_in, const int* in_sizes, int n_in,
                              void* d_out, int out_size, void* d_ws, size_t ws_size,
                              hipStream_t stream) {
  const float* x  = (const float*)d_in[0];
  const float* W1 = (const float*)d_in[1];
  const float* b1 = (const float*)d_in[2];
  const float* W2 = (const float*)d_in[3];
  const float* b2 = (const float*)d_in[4];
  float* out = (float*)d_out;

  char* ws = (char*)d_ws;
  // z aliases xs ([M][512] bf16, identical layout): gemm2 reads xs(gm,gn) then writes
  // z(gm,gn) from the SAME thread (read-before-write in the readback loop), tiles disjoint
  // across blocks -> safe.
  unsigned* xs  = (unsigned*)(ws);                           // 32 MiB bf16 xs
  bf16*     xsb = (bf16*)(ws);
  bf16*     z   = (bf16*)(ws);                               // aliases xs
  unsigned* srt = (unsigned*)(ws + 33554432);                // 32 MiB u16 srt
  bf16* h   = (bf16*)(ws + 67108864);                        // 128 MiB
  bf16* W1b = (bf16*)(ws + 201326592);                       // 2 MiB
  bf16* W2b = (bf16*)(ws + 203423744);                       // 2 MiB

  cvt_pair<<<(HH * FF + 255) / 256, 256, 0, stream>>>(W1, W1b, W2, W2b, HH * FF);
  sort_rows_wave<<<M_ROWS / 4, 256, 0, stream>>>(x, xs, srt);
  // h = relu(xs @ W1^T + b1): M=32768, K=512, N=2048  (1D grid, XCD-chunked remap inside)
  gemm8p<1, 0, FF, HH><<<(M_ROWS / 256) * (HH / 256), 512, 0, stream>>>(xsb, W1b, b1, nullptr, h);
  // z = h @ W2^T + b2 + xs: M=32768, K=2048, N=512  (skip fused, sorted domain)
  gemm8p<0, 1, HH, FF><<<(M_ROWS / 256) * (FF / 256), 512, 0, stream>>>(h, W2b, b2, xsb, z);
  permute_gather<<<M_ROWS / 4, 256, 0, stream>>>(z, srt, out);
}

// Round 8
// 343.322 us; speedup vs baseline: 1.8578x; 1.0553x over previous
//
#include <hip/hip_runtime.h>
#include <hip/hip_bf16.h>

typedef __hip_bfloat16 bf16;
typedef __attribute__((ext_vector_type(8))) short bf16x8;   // 8 bf16 = 4 VGPRs (MFMA A/B frag)
typedef __attribute__((ext_vector_type(4))) float f32x4;    // MFMA C/D frag

#define ASYNC_CP16(gsrc, ldst)                                                              \
  __builtin_amdgcn_global_load_lds(                                                         \
      (const __attribute__((address_space(1))) unsigned int*)(gsrc),                        \
      (__attribute__((address_space(3))) unsigned int*)(ldst), 16, 0, 0)

#define BB 32
#define NN 1024
#define FF 512
#define HH 2048
#define M_ROWS (BB * NN)  // 32768

// ---------------------------------------------------------------- weight casts (fused)
__global__ __launch_bounds__(256) void cvt_pair(const float* __restrict__ a, bf16* __restrict__ da,
                                                const float* __restrict__ b, bf16* __restrict__ db,
                                                int n) {
  int i = blockIdx.x * 256 + threadIdx.x;
  if (i < n) {
    da[i] = __float2bfloat16(a[i]);
    db[i] = __float2bfloat16(b[i]);
  }
}

// ---------------------------------------------------------------- cross-lane xor via LDS crossbar
template <int IMM>
__device__ __forceinline__ unsigned long long swz64(unsigned long long k) {
  int lo = __builtin_amdgcn_ds_swizzle((int)(unsigned)k, IMM);
  int hi = __builtin_amdgcn_ds_swizzle((int)(unsigned)(k >> 32), IMM);
  return (((unsigned long long)(unsigned)hi) << 32) | (unsigned)lo;
}

// ---------------------------------------------------------------- stable argsort per row
// (unchanged from R3/R4 passing version)
__global__ __launch_bounds__(256) void sort_rows_wave(const float* __restrict__ x,
                                                      unsigned* __restrict__ xs_pack,
                                                      unsigned* __restrict__ srt_pack) {
  __shared__ __align__(16) unsigned short scatx[4 * FF];
  const int t = threadIdx.x;
  const int lane = t & 63;
  const int w = t >> 6;
  const size_t row = (size_t)blockIdx.x * 4 + w;
  const float* xr = x + row * FF;

  float4 v0 = *(const float4*)(xr + lane * 8);
  float4 v1 = *(const float4*)(xr + lane * 8 + 4);
  float vals[8] = {v0.x, v0.y, v0.z, v0.w, v1.x, v1.y, v1.z, v1.w};

  unsigned long long key[8];
#pragma unroll
  for (int r = 0; r < 8; r++) {
    unsigned u = __float_as_uint(vals[r]);
    unsigned s = u ^ ((unsigned)((int)u >> 31) | 0x80000000u);  // monotone fp32->u32
    key[r] = ((unsigned long long)s << 32) | (unsigned)(lane * 8 + r);
  }

#pragma unroll
  for (int k = 2; k <= 512; k <<= 1) {
#pragma unroll
    for (int j = k >> 1; j > 0; j >>= 1) {
      if (j >= 8) {
        const int d = j >> 3;
        unsigned long long o[8];
#pragma unroll
        for (int r = 0; r < 8; r++) {
          if (d == 1)       o[r] = swz64<0x041F>(key[r]);
          else if (d == 2)  o[r] = swz64<0x081F>(key[r]);
          else if (d == 4)  o[r] = swz64<0x101F>(key[r]);
          else if (d == 8)  o[r] = swz64<0x201F>(key[r]);
          else if (d == 16) o[r] = swz64<0x401F>(key[r]);
          else              o[r] = __shfl_xor(key[r], 32, 64);
        }
        bool asc = (((lane * 8) & k) == 0);
        bool lower = ((lane & d) == 0);
        bool keep = (asc == lower);
#pragma unroll
        for (int r = 0; r < 8; r++) {
          bool mine = key[r] < o[r];
          key[r] = (mine == keep) ? key[r] : o[r];
        }
      } else {
#pragma unroll
        for (int r = 0; r < 8; r++) {
          if ((r & j) == 0) {
            const int a = r, b = r | j;
            bool asc = (((lane * 8 + a) & k) == 0);
            unsigned long long ka = key[a], kb = key[b];
            bool sw = ((ka > kb) == asc);
            key[a] = sw ? kb : ka;
            key[b] = sw ? ka : kb;
          }
        }
      }
    }
  }

  const int base = w * FF;
  unsigned j8[8];
#pragma unroll
  for (int r = 0; r < 8; r++) {
    j8[r] = (unsigned)key[r] & 0xFFFFu;
    __hip_bfloat16 hb = __float2bfloat16(vals[r]);
    scatx[base + j8[r]] = *(unsigned short*)&hb;
  }

  uint4 so;
  so.x = j8[0] | (j8[1] << 16);
  so.y = j8[2] | (j8[3] << 16);
  so.z = j8[4] | (j8[5] << 16);
  so.w = j8[6] | (j8[7] << 16);
  *(uint4*)(srt_pack + row * 256 + lane * 4) = so;

  __syncthreads();
  uint4 xo = *(const uint4*)&scatx[base + lane * 8];
  *(uint4*)(xs_pack + row * 256 + lane * 4) = xo;
}

// ---------------------------------------------------------------- 2-phase 256x256 GEMM
// (T1 XCD remap + T2 swizzle + T4 counted vmcnt R4-cadence + T5 setprio + R8 phase-merge)
// R8 change vs R4: merge each K-tile's 4 phases into 2. Per phase: issue ALL 12 ds_reads
// (af-mh0 x4, bq x4 | sched_barrier | af-mh1 x4), stage 4 loads, ONE barrier, then
// lgkmcnt(4) -> 16 MFMA (mh0) -> lgkmcnt(0) -> 16 MFMA (mh1): the mh1 A-reads' LDS latency
// hides under mh0's MFMA burst, and barriers drop 8 -> 4 per K-tile.
// vmcnt ledger identical to R4 (4 staged/phase, vmcnt(4) each phase end):
//   end-A: 4 old (kt,ks1) + 4 new -> vmcnt(4) completes (kt,ks1) for phase B.
//   end-B: 8 of tile kt+1 -> vmcnt(4) completes (kt+1,ks0) for next phase A.
// Slot overwrite distance: stage(kt+1,ks) overwrites slot last read 4 barriers earlier. Safe.
// Epilogue: R4 direct stores (R7's LDS-transpose epilogue regressed; reverted).
template <int RELU, int ADDX, int K, int N>
__global__ __launch_bounds__(512, 2) void gemm8p(const bf16* __restrict__ A,
                                                 const bf16* __restrict__ Bw,
                                                 const float* __restrict__ bias,
                                                 const bf16* __restrict__ xs_add,
                                                 bf16* __restrict__ C) {
  __shared__ __align__(16) bf16 S[65536];  // 128 KiB
  const int t = threadIdx.x;
  const int lane = t & 63, wave = t >> 6;
  const int waveM = wave >> 2, waveN = wave & 3;

  constexpr int GY = N / 256;                       // blocks in the N dimension
  static_assert((M_ROWS / 256) % 8 == 0, "x-chunking assumes 16 x per XCD");
  const int g = (int)blockIdx.x;
  const int q = g >> 3;
  const size_t mBase = (size_t)((g & 7) * ((M_ROWS / 256) / 8) + q / GY) * 256;
  const size_t nBase = (size_t)(q % GY) * 256;

  // staging: thread covers 16B slot s = t (+512 for second load); row = s>>2, pre-swizzled col
  const int srow = t >> 2;                        // 0..127 (second load: +128)
  const int sclog = (t & 3) ^ ((t >> 3) & 3);     // inverse-swizzled source col slot
  const bf16* Asrc0 = A + (mBase + srow) * (size_t)K + sclog * 8;
  const bf16* Bsrc0 = Bw + (nBase + srow) * (size_t)K + sclog * 8;
  const int sdA = wave * 512;                     // LDS dest (elements), + region base
  const int sdB = 32768 + wave * 512;

  // fragment reads: row = (tile-row) + fr, swizzled 16B slot = (lane>>4) ^ ((fr>>1)&3)
  const int fr = lane & 15;
  const int swz8 = ((lane >> 4) ^ ((lane >> 1) & 3)) * 8;
  const int aRd = (waveM * 128 + fr) * 32 + swz8;           // + region + mh*2048 + i*512
  const int bRd = 32768 + (waveN * 64 + fr) * 32 + swz8;    // + region(buf,ks) + nt*512

#define STAGE_A(tt, ks)                                           \
  do {                                                            \
    const int rb_ = (((tt) & 1) * 2 + (ks)) * 8192 + sdA;         \
    const bf16* g_ = Asrc0 + (size_t)(tt) * 64 + (ks) * 32;       \
    ASYNC_CP16(g_, &S[rb_]);                                      \
    ASYNC_CP16(g_ + (size_t)128 * K, &S[rb_ + 4096]);             \
  } while (0)
#define STAGE_B(tt, ks)                                           \
  do {                                                            \
    const int rb_ = (((tt) & 1) * 2 + (ks)) * 8192 + sdB;         \
    const bf16* g_ = Bsrc0 + (size_t)(tt) * 64 + (ks) * 32;       \
    ASYNC_CP16(g_, &S[rb_]);                                      \
    ASYNC_CP16(g_ + (size_t)128 * K, &S[rb_ + 4096]);             \
  } while (0)

  f32x4 acc[8][4];
  f32x4 zero = {0.f, 0.f, 0.f, 0.f};
#pragma unroll
  for (int i = 0; i < 8; i++)
#pragma unroll
    for (int j = 0; j < 4; j++) acc[i][j] = zero;

  // prologue: stage tile 0 fully; k0 halves guaranteed, k1 halves stay in flight
  STAGE_A(0, 0);
  STAGE_B(0, 0);
  STAGE_A(0, 1);
  STAGE_B(0, 1);
  asm volatile("s_waitcnt vmcnt(4)" ::: "memory");
  __builtin_amdgcn_s_barrier();

  const int NT = K / 64;
  for (int kt = 0; kt < NT; ++kt) {
    const int buf = kt & 1;
    const bool pf = (kt + 1 < NT);
    bf16x8 af0[4], af1[4], bq[4];

    // ---- Phase A (ks=0): 12 reads (order-pinned), stage (kt+1,0)
    {
      const int rg = buf * 16384;
#pragma unroll
      for (int i = 0; i < 4; i++) af0[i] = *(const bf16x8*)&S[rg + aRd + i * 512];
#pragma unroll
      for (int n = 0; n < 4; n++) bq[n] = *(const bf16x8*)&S[rg + bRd + n * 512];
      __builtin_amdgcn_sched_barrier(0);  // pin issue order: af0+bq before af1
#pragma unroll
      for (int i = 0; i < 4; i++) af1[i] = *(const bf16x8*)&S[rg + aRd + 2048 + i * 512];
      if (pf) {
        STAGE_A(kt + 1, 0);
        STAGE_B(kt + 1, 0);
      }
      __builtin_amdgcn_s_barrier();
      asm volatile("s_waitcnt lgkmcnt(4)" ::: "memory");  // af0+bq complete; af1 in flight
      __builtin_amdgcn_sched_barrier(0);
      __builtin_amdgcn_s_setprio(1);
#pragma unroll
      for (int i = 0; i < 4; i++)
#pragma unroll
        for (int n = 0; n < 4; n++)
          acc[i][n] = __builtin_amdgcn_mfma_f32_16x16x32_bf16(af0[i], bq[n], acc[i][n], 0, 0, 0);
      asm volatile("s_waitcnt lgkmcnt(0)" ::: "memory");  // af1 complete (hidden under mh0)
      __builtin_amdgcn_sched_barrier(0);
#pragma unroll
      for (int i = 0; i < 4; i++)
#pragma unroll
        for (int n = 0; n < 4; n++)
          acc[4 + i][n] = __builtin_amdgcn_mfma_f32_16x16x32_bf16(af1[i], bq[n], acc[4 + i][n], 0, 0, 0);
      __builtin_amdgcn_s_setprio(0);
      if (pf) asm volatile("s_waitcnt vmcnt(4)" ::: "memory");  // completes (kt,ks1)
      else    asm volatile("s_waitcnt vmcnt(0)" ::: "memory");
      __builtin_amdgcn_s_barrier();
    }
    // ---- Phase B (ks=1): 12 reads, stage (kt+1,1)
    {
      const int rg = buf * 16384 + 8192;
#pragma unroll
      for (int i = 0; i < 4; i++) af0[i] = *(const bf16x8*)&S[rg + aRd + i * 512];
#pragma unroll
      for (int n = 0; n < 4; n++) bq[n] = *(const bf16x8*)&S[rg + bRd + n * 512];
      __builtin_amdgcn_sched_barrier(0);
#pragma unroll
      for (int i = 0; i < 4; i++) af1[i] = *(const bf16x8*)&S[rg + aRd + 2048 + i * 512];
      if (pf) {
        STAGE_A(kt + 1, 1);
        STAGE_B(kt + 1, 1);
      }
      __builtin_amdgcn_s_barrier();
      asm volatile("s_waitcnt lgkmcnt(4)" ::: "memory");
      __builtin_amdgcn_sched_barrier(0);
      __builtin_amdgcn_s_setprio(1);
#pragma unroll
      for (int i = 0; i < 4; i++)
#pragma unroll
        for (int n = 0; n < 4; n++)
          acc[i][n] = __builtin_amdgcn_mfma_f32_16x16x32_bf16(af0[i], bq[n], acc[i][n], 0, 0, 0);
      asm volatile("s_waitcnt lgkmcnt(0)" ::: "memory");
      __builtin_amdgcn_sched_barrier(0);
#pragma unroll
      for (int i = 0; i < 4; i++)
#pragma unroll
        for (int n = 0; n < 4; n++)
          acc[4 + i][n] = __builtin_amdgcn_mfma_f32_16x16x32_bf16(af1[i], bq[n], acc[4 + i][n], 0, 0, 0);
      __builtin_amdgcn_s_setprio(0);
      if (pf) asm volatile("s_waitcnt vmcnt(4)" ::: "memory");  // completes (kt+1,ks0)
      __builtin_amdgcn_s_barrier();
    }
  }
#undef STAGE_A
#undef STAGE_B

  // epilogue: R4 direct stores. C/D layout col=lane&15, row=(lane>>4)*4+reg (verified)
  const int cn = lane & 15;
  const int cm = (lane >> 4) * 4;
  float b4[4];
#pragma unroll
  for (int n = 0; n < 4; n++) b4[n] = bias[nBase + waveN * 64 + n * 16 + cn];
#pragma unroll
  for (int mt = 0; mt < 8; mt++) {
#pragma unroll
    for (int n = 0; n < 4; n++) {
      size_t gn = nBase + waveN * 64 + n * 16 + cn;
#pragma unroll
      for (int r = 0; r < 4; r++) {
        size_t gm = mBase + waveM * 128 + mt * 16 + cm + r;
        float v = acc[mt][n][r] + b4[n];
        if (RELU) v = fmaxf(v, 0.f);
        if (ADDX) v += __bfloat162float(xs_add[gm * (size_t)N + gn]);
        C[gm * (size_t)N + gn] = __float2bfloat16(v);
      }
    }
  }
}

// ---------------------------------------------------------------- final permute (pure gather)
__global__ __launch_bounds__(256) void permute_gather(const bf16* __restrict__ zp,
                                                      const unsigned* __restrict__ srt_pack,
                                                      float* __restrict__ out) {
  __shared__ __align__(16) unsigned short zr[4][FF];
  const int t = threadIdx.x;
  const int lane = t & 63;
  const int w = t >> 6;
  const size_t row = (size_t)blockIdx.x * 4 + w;

  *(uint4*)&zr[w][lane * 8] = *(const uint4*)(zp + row * FF + lane * 8);
  uint4 sv = *(const uint4*)(srt_pack + row * 256 + lane * 4);
  __syncthreads();

  unsigned idx[8] = {sv.x & 0xFFFFu, sv.x >> 16, sv.y & 0xFFFFu, sv.y >> 16,
                     sv.z & 0xFFFFu, sv.z >> 16, sv.w & 0xFFFFu, sv.w >> 16};
  float4 o0, o1;
#pragma unroll
  for (int r = 0; r < 8; r++) {
    float zf = __uint_as_float(((unsigned)zr[w][idx[r]]) << 16);
    ((r < 4) ? (&o0.x) : (&o1.x))[r & 3] = zf;
  }
  *(float4*)(out + row * FF + lane * 8) = o0;
  *(float4*)(out + row * FF + lane * 8 + 4) = o1;
}

// ---------------------------------------------------------------- launch
extern "C" void kernel_launch(void* const* d_in, const int* in_sizes, int n_in,
                              void* d_out, int out_size, void* d_ws, size_t ws_size,
                              hipStream_t stream) {
  const float* x  = (const float*)d_in[0];
  const float* W1 = (const float*)d_in[1];
  const float* b1 = (const float*)d_in[2];
  const float* W2 = (const float*)d_in[3];
  const float* b2 = (const float*)d_in[4];
  float* out = (float*)d_out;

  char* ws = (char*)d_ws;
  // z aliases xs ([M][512] bf16, identical layout): gemm2 reads xs(gm,gn) then writes
  // z(gm,gn) from the SAME thread, tiles disjoint across blocks -> safe.
  unsigned* xs  = (unsigned*)(ws);                           // 32 MiB bf16 xs
  bf16*     xsb = (bf16*)(ws);
  bf16*     z   = (bf16*)(ws);                               // aliases xs
  unsigned* srt = (unsigned*)(ws + 33554432);                // 32 MiB u16 srt
  bf16* h   = (bf16*)(ws + 67108864);                        // 128 MiB
  bf16* W1b = (bf16*)(ws + 201326592);                       // 2 MiB
  bf16* W2b = (bf16*)(ws + 203423744);                       // 2 MiB

  cvt_pair<<<(HH * FF + 255) / 256, 256, 0, stream>>>(W1, W1b, W2, W2b, HH * FF);
  sort_rows_wave<<<M_ROWS / 4, 256, 0, stream>>>(x, xs, srt);
  // h = relu(xs @ W1^T + b1): M=32768, K=512, N=2048  (1D grid, XCD-chunked remap inside)
  gemm8p<1, 0, FF, HH><<<(M_ROWS / 256) * (HH / 256), 512, 0, stream>>>(xsb, W1b, b1, nullptr, h);
  // z = h @ W2^T + b2 + xs: M=32768, K=2048, N=512  (skip fused, sorted domain)
  gemm8p<0, 1, HH, FF><<<(M_ROWS / 256) * (FF / 256), 512, 0, stream>>>(h, W2b, b2, xsb, z);
  permute_gather<<<M_ROWS / 4, 256, 0, stream>>>(z, srt, out);
}